// Round 7
// baseline (228.316 us; speedup 1.0000x reference)
//
#include <hip/hip_runtime.h>

#define B 8
#define N 1024
#define E 10
#define GP 44                        // 4 emb rows packed in 44 floats (40 data + 4 pad)
#define EMB_FLOATS (256 * GP)        // 11264 floats per batch
#define EMB_F4 (EMB_FLOATS / 4)      // 2816 float4 per batch
#define NBLK 256                     // 8 batches x 32 tiles of 32 rows
#define TPB 32                       // blocks per batch (barrier domain)
#define BAR_PAD 32                   // 32 uints = 128 B between counters

typedef float f32x4 __attribute__((ext_vector_type(4)));

// ---------------------------------------------------------------------------
// Fence-free PER-BATCH barrier (32 blocks). All cross-block data moves via
// sc0|sc1 write-through stores and sc0|sc1 bypass loads, so no buffer_wbl2 /
// buffer_inv is needed. __syncthreads() drains vmcnt(0) for every wave before
// s_barrier, so all write-through stores are LLC-visible before the counter
// increment. Each counter on its own 128 B line; batches fully decoupled.
// ---------------------------------------------------------------------------
__device__ __forceinline__ void batch_barrier(unsigned* cnt) {
    __syncthreads();   // s_waitcnt vmcnt(0) lgkmcnt(0) + s_barrier per wave
    if (threadIdx.x == 0) {
        __hip_atomic_fetch_add(cnt, 1u, __ATOMIC_RELAXED, __HIP_MEMORY_SCOPE_AGENT);
        while (__hip_atomic_load(cnt, __ATOMIC_RELAXED, __HIP_MEMORY_SCOPE_AGENT) < TPB)
            __builtin_amdgcn_s_sleep(2);
    }
    __syncthreads();
    asm volatile("" ::: "memory");   // compiler ordering only
}

// write-through to LLC (agent-visible once vmcnt drains)
__device__ __forceinline__ void store_llc(float* p, float v) {
    __hip_atomic_store((unsigned*)p, __float_as_uint(v),
                       __ATOMIC_RELAXED, __HIP_MEMORY_SCOPE_AGENT);
}
__device__ __forceinline__ float load_llc(const float* p) {
    unsigned u = __hip_atomic_load((const unsigned*)p,
                                   __ATOMIC_RELAXED, __HIP_MEMORY_SCOPE_AGENT);
    return __uint_as_float(u);
}

// ---------------------------------------------------------------------------
// Fully fused kernel. 256 blocks (8 b x 32 tiles of 32 rows) x 1024 threads
// = 1 block/CU, 16 waves/CU.
// NEW decomposition (halves LDS-read traffic vs round 6):
//   thread: rs = tid>>7 (4 rows i0+4rs+rr), jg = tid&127 (j-groups jg, jg+128)
//   -> 320 B LDS read + 320 FMA per thread per iteration (was 640 B / 320).
//   acc[4][10] = 40 VGPR; butterfly masks 1,2,4,8 (intra-row-16 => DPP/VALU)
//   -> 4 partials per wave into vred[16][5][40] (strides 200/40 = 8 mod 32).
// Phase 0: base via relu-collapse, 32 cols/block == this tile's rows; base
//   stays in REGISTER b_reg (tid<320); emb0 = relu(base) -> eA (LLC stores).
// Iterations x4: stage whole-batch emb to LDS via sc0|sc1 bypass loads,
//   v = A@emb with A register-resident (loaded ONCE), out = relu(b_reg+v@Wp^T).
// Final: emb_out + q epilogue via qpart tree across one more per-batch barrier.
// ---------------------------------------------------------------------------
__global__ __launch_bounds__(1024, 4) void k_fused(
    const float* __restrict__ W, const float* __restrict__ features,
    const float* __restrict__ w_sel, const float* __restrict__ w_nbw,
    const float* __restrict__ w_ew, const float* __restrict__ A,
    const float* __restrict__ Wp, const float* __restrict__ w_reduc,
    const float* __restrict__ w_all, const float* __restrict__ w_act,
    float* eA, float* eB,
    float* __restrict__ emb_out, float* __restrict__ qv,
    float* __restrict__ qpart, unsigned* __restrict__ bars)
{
    __shared__ float4 EmS[EMB_F4];        // 45056 B (phase 0 overlays scratch)
    __shared__ float vred[16][5][4 * E];  // 12800 B (strides 200/40: 8 mod 32)
    __shared__ float WpS[E * E];
    __shared__ float gaS[E], gactS[E];
    __shared__ float vS[32 * E], qS[32 * E], qrow[32];
    __shared__ float qsumS;

    int bx = blockIdx.x, tid = threadIdx.x;
    int b = bx >> 5, tile = bx & 31;
    int i0 = tile * 32;
    int w = tid >> 6;     // wave 0..15
    int s = tid & 63;     // lane
    int rs = tid >> 7;    // row-set 0..7: rows i0 + 4*rs + rr
    int jg = tid & 127;   // j-group: j = 4*(jg + 128c) + q
    unsigned* mybars = bars + b * BAR_PAD;   // stage st: mybars[st * B * BAR_PAD]

    // ---- A tile (32 rows) -> registers, ONCE (8 coalesced float4/thread;
    //      latency hides under phase-0's W stream) ----
    float Arf[4][2][4];
    {
        const float* Ab = A + ((size_t)(b * N) + i0 + (rs << 2)) * N + 4 * jg;
#pragma unroll
        for (int rr = 0; rr < 4; ++rr)
#pragma unroll
            for (int c = 0; c < 2; ++c) {
                float4 t = *(const float4*)(Ab + (size_t)rr * N + 512 * c);
                Arf[rr][c][0] = t.x; Arf[rr][c][1] = t.y;
                Arf[rr][c][2] = t.z; Arf[rr][c][3] = t.w;
            }
    }

    if (tid < E * E) WpS[tid] = Wp[tid];
    if (tid < E) {
        float sa = 0.f, sc = 0.f;
#pragma unroll
        for (int k = 0; k < E; ++k) {
            sa += w_reduc[k] * w_all[k * E + tid];
            sc += w_reduc[E + k] * w_act[k * E + tid];
        }
        gaS[tid] = sa;
        gactS[tid] = sc;
    }

    // ---- phase 0: base + emb0 via relu-collapse, 32 cols/block ----
    float b_reg = 0.f;
    {
        float* redPt = (float*)&EmS[0];       // [32][129] transposed scratch
        float* redNt = redPt + 32 * 129;      // [32][129]
        float* scol  = redNt + 32 * 129;      // [2][32]
        int c4 = (tid & 7) * 4;               // float4 col group within 32 cols
        int rg = tid >> 3;                    // 128 row-groups x 8 rows
        const float* wp = W + ((size_t)b * N + rg * 8) * N + i0 + c4;
        float4 sp = {0.f, 0.f, 0.f, 0.f}, sn = {0.f, 0.f, 0.f, 0.f};
#pragma unroll
        for (int i = 0; i < 8; ++i) {
            float4 ww = *(const float4*)(wp + (size_t)i * N);
            sp.x += fmaxf(ww.x, 0.f); sn.x += fmaxf(-ww.x, 0.f);
            sp.y += fmaxf(ww.y, 0.f); sn.y += fmaxf(-ww.y, 0.f);
            sp.z += fmaxf(ww.z, 0.f); sn.z += fmaxf(-ww.z, 0.f);
            sp.w += fmaxf(ww.w, 0.f); sn.w += fmaxf(-ww.w, 0.f);
        }
        redPt[(c4 + 0) * 129 + rg] = sp.x; redNt[(c4 + 0) * 129 + rg] = sn.x;
        redPt[(c4 + 1) * 129 + rg] = sp.y; redNt[(c4 + 1) * 129 + rg] = sn.y;
        redPt[(c4 + 2) * 129 + rg] = sp.z; redNt[(c4 + 2) * 129 + rg] = sn.z;
        redPt[(c4 + 3) * 129 + rg] = sp.w; redNt[(c4 + 3) * 129 + rg] = sn.w;
        __syncthreads();
        if (tid < 64) {
            int cc = tid & 31;
            const float* rp = (tid < 32) ? redPt : redNt;
            float t = 0.f;
#pragma unroll 8
            for (int g = 0; g < 128; ++g) t += rp[cc * 129 + g];
            scol[(tid >> 5) * 32 + cc] = t;
        }
        __syncthreads();
        if (tid < 32 * E) {
            int cc = tid / E, f = tid % E;
            float spc = scol[cc], snc = scol[32 + cc];
            float acc = features[(b << 10) + i0 + cc] * w_sel[f];
#pragma unroll
            for (int e = 0; e < E; ++e) {
                float ce = w_ew[e];
                float se = (ce > 0.f) ? ce * spc : (-ce) * snc;
                acc += w_nbw[f * E + e] * se;
            }
            b_reg = acc;                       // base stays in register
            int row = i0 + cc;
            store_llc(&eA[(size_t)b * EMB_FLOATS + (row >> 2) * GP + (row & 3) * E + f],
                      fmaxf(acc, 0.f));        // emb after ref iter 1
        }
    }
    batch_barrier(&mybars[0]);

    // ---- 4 remaining reference iterations, A tile register-resident ----
    float da = 0.f;
    for (int it = 0; it < 4; ++it) {
        const float* ein = (it & 1) ? (const float*)eB : (const float*)eA;
        float* eout = (it & 1) ? eA : eB;

        // stage whole-batch emb: 3 LLC-bypass float4 loads/thread, ds_writes
        {
            const f32x4* src = (const f32x4*)ein + (size_t)b * EMB_F4;
            f32x4 t0, t1, t2 = {0.f, 0.f, 0.f, 0.f};
            asm volatile("global_load_dwordx4 %0, %1, off sc0 sc1"
                         : "=v"(t0) : "v"(src + tid) : "memory");
            asm volatile("global_load_dwordx4 %0, %1, off sc0 sc1"
                         : "=v"(t1) : "v"(src + tid + 1024) : "memory");
            if (tid < EMB_F4 - 2048)           // 768: waves 12-15 skip (uniform)
                asm volatile("global_load_dwordx4 %0, %1, off sc0 sc1"
                             : "=v"(t2) : "v"(src + tid + 2048) : "memory");
            asm volatile("s_waitcnt vmcnt(0)" ::: "memory");
            __builtin_amdgcn_sched_barrier(0);
            ((f32x4*)EmS)[tid]        = t0;
            ((f32x4*)EmS)[tid + 1024] = t1;
            if (tid < EMB_F4 - 2048) ((f32x4*)EmS)[tid + 2048] = t2;
        }
        __syncthreads();

        float acc[4][E];
#pragma unroll
        for (int rr = 0; rr < 4; ++rr)
#pragma unroll
            for (int e = 0; e < E; ++e) acc[rr][e] = 0.f;

#pragma unroll
        for (int c = 0; c < 2; ++c) {
            const float4* gp = EmS + (size_t)(jg + 128 * c) * (GP / 4);
            // first half of group: rows q=0,1 (floats 0..19)
            {
                float4 g4a[5];
#pragma unroll
                for (int t = 0; t < 5; ++t) g4a[t] = gp[t];
                const float* ga = (const float*)g4a;
#pragma unroll
                for (int q = 0; q < 2; ++q)
#pragma unroll
                    for (int rr = 0; rr < 4; ++rr) {
                        float a = Arf[rr][c][q];
#pragma unroll
                        for (int e = 0; e < E; ++e)
                            acc[rr][e] += a * ga[q * E + e];
                    }
            }
            // second half: rows q=2,3 (floats 20..39)
            {
                float4 g4b[5];
#pragma unroll
                for (int t = 0; t < 5; ++t) g4b[t] = gp[5 + t];
                const float* gb = (const float*)g4b;
#pragma unroll
                for (int q = 0; q < 2; ++q)
#pragma unroll
                    for (int rr = 0; rr < 4; ++rr) {
                        float a = Arf[rr][c][q + 2];
#pragma unroll
                        for (int e = 0; e < E; ++e)
                            acc[rr][e] += a * gb[q * E + e];
                    }
            }
        }

        // reduce 64 lanes -> 4 partials per wave (masks 1,2,4,8: DPP/VALU)
#pragma unroll
        for (int mask = 1; mask <= 8; mask <<= 1)
#pragma unroll
            for (int rr = 0; rr < 4; ++rr)
#pragma unroll
                for (int e = 0; e < E; ++e)
                    acc[rr][e] += __shfl_xor(acc[rr][e], mask, 64);
        if ((s & 15) == 0)
#pragma unroll
            for (int rr = 0; rr < 4; ++rr)
#pragma unroll
                for (int e = 0; e < E; ++e)
                    vred[w][s >> 4][rr * E + e] = acc[rr][e];
        __syncthreads();

        if (tid < 32 * E) {
            int r = tid / E, f = tid % E;
            int prs = r >> 2, rr = r & 3;
            float v[E];
#pragma unroll
            for (int e = 0; e < E; ++e) {
                float t = 0.f;
#pragma unroll
                for (int h = 0; h < 2; ++h)
#pragma unroll
                    for (int p = 0; p < 4; ++p)
                        t += vred[(prs << 1) + h][p][rr * E + e];
                v[e] = t;
            }
            float d = 0.f;
#pragma unroll
            for (int e = 0; e < E; ++e) d += v[e] * WpS[f * E + e];
            float r_out = fmaxf(b_reg + d, 0.f);
            if (it < 3) {
                int grow = i0 + r;
                store_llc(&eout[(size_t)b * EMB_FLOATS + (grow >> 2) * GP + (grow & 3) * E + f],
                          r_out);
            } else {
                size_t gi = (size_t)((b << 10) + i0 + r);
                emb_out[gi * E + f] = r_out;
                vS[tid] = r_out * gactS[f];
                qS[tid] = r_out * gaS[f];
            }
        }
        if (it < 3) batch_barrier(&mybars[(1 + it) * B * BAR_PAD]);
    }

    // ---- q epilogue: per-tile partials, one barrier, deterministic sum ----
    __syncthreads();
    if (tid < 32) {
        float dg = 0.f;
#pragma unroll
        for (int f = 0; f < E; ++f) {
            da += vS[tid * E + f];
            dg += qS[tid * E + f];
        }
        qrow[tid] = dg;
    }
    __syncthreads();
    if (tid == 0) {
        float t = 0.f;
#pragma unroll
        for (int r = 0; r < 32; ++r) t += qrow[r];
        store_llc(&qpart[bx], t);
    }
    batch_barrier(&mybars[4 * B * BAR_PAD]);

    if (tid < 32) {
        float t = load_llc(&qpart[(b << 5) + tid]);
#pragma unroll
        for (int mask = 1; mask < 32; mask <<= 1)
            t += __shfl_xor(t, mask, 32);
        if (tid == 0) qsumS = t;
    }
    __syncthreads();
    if (tid < 32) qv[(b << 10) + i0 + tid] = da + qsumS;
}

extern "C" void kernel_launch(void* const* d_in, const int* in_sizes, int n_in,
                              void* d_out, int out_size, void* d_ws, size_t ws_size,
                              hipStream_t stream) {
    const float* features  = (const float*)d_in[0];
    const float* W         = (const float*)d_in[1];
    const float* adjacency = (const float*)d_in[2];
    const float* w_sel     = (const float*)d_in[3];
    const float* w_pri     = (const float*)d_in[4];
    const float* w_nbw     = (const float*)d_in[5];
    const float* w_ew      = (const float*)d_in[6];
    const float* w_reduc   = (const float*)d_in[7];
    const float* w_all     = (const float*)d_in[8];
    const float* w_act     = (const float*)d_in[9];

    float* out     = (float*)d_out;
    float* qv      = out;              // B*N
    float* emb_out = out + B * N;      // B*N*E

    float* ws      = (float*)d_ws;
    float* eA      = ws;                               // B*EMB_FLOATS
    float* eB      = eA + (size_t)B * EMB_FLOATS;
    float* qpart   = eB + (size_t)B * EMB_FLOATS;      // 256 floats
    unsigned* bars = (unsigned*)(qpart + NBLK);        // 5 stages x 8 batches x 128B

    hipMemsetAsync(bars, 0, 5 * B * BAR_PAD * sizeof(unsigned), stream);
    k_fused<<<NBLK, 1024, 0, stream>>>(W, features, w_sel, w_nbw, w_ew,
                                       adjacency, w_pri, w_reduc, w_all, w_act,
                                       eA, eB, emb_out, qv, qpart, bars);
}

// Round 8
// 227.983 us; speedup vs baseline: 1.0015x; 1.0015x over previous
//
#include <hip/hip_runtime.h>

#define B 8
#define N 1024
#define E 10
#define GP 44                        // 4 emb rows packed in 44 floats (40 data + 4 pad)
#define EMB_FLOATS (256 * GP)        // 11264 floats per batch
#define EMB_F4 (EMB_FLOATS / 4)      // 2816 float4 per batch
#define NBLK 256                     // 8 batches x 32 tiles of 32 rows
#define TPB 32                       // blocks per batch (barrier domain)
#define BAR_PAD 32                   // 32 uints = 128 B between counters

typedef float f32x4 __attribute__((ext_vector_type(4)));

// ---------------------------------------------------------------------------
// Fence-free PER-BATCH barrier (32 blocks). All cross-block data moves via
// sc0|sc1 write-through stores and sc0|sc1 bypass loads, so no buffer_wbl2 /
// buffer_inv is needed. __syncthreads() drains vmcnt(0) for every wave before
// s_barrier, so all write-through stores are LLC-visible before the counter
// increment. Each counter on its own 128 B line; batches fully decoupled.
// ---------------------------------------------------------------------------
__device__ __forceinline__ void batch_barrier(unsigned* cnt) {
    __syncthreads();   // s_waitcnt vmcnt(0) lgkmcnt(0) + s_barrier per wave
    if (threadIdx.x == 0) {
        __hip_atomic_fetch_add(cnt, 1u, __ATOMIC_RELAXED, __HIP_MEMORY_SCOPE_AGENT);
        while (__hip_atomic_load(cnt, __ATOMIC_RELAXED, __HIP_MEMORY_SCOPE_AGENT) < TPB)
            __builtin_amdgcn_s_sleep(2);
    }
    __syncthreads();
    asm volatile("" ::: "memory");   // compiler ordering only
}

// write-through to LLC (agent-visible once vmcnt drains)
__device__ __forceinline__ void store_llc(float* p, float v) {
    __hip_atomic_store((unsigned*)p, __float_as_uint(v),
                       __ATOMIC_RELAXED, __HIP_MEMORY_SCOPE_AGENT);
}
__device__ __forceinline__ float load_llc(const float* p) {
    unsigned u = __hip_atomic_load((const unsigned*)p,
                                   __ATOMIC_RELAXED, __HIP_MEMORY_SCOPE_AGENT);
    return __uint_as_float(u);
}

// ---------------------------------------------------------------------------
// Fully fused kernel. 256 blocks (8 b x 32 tiles of 32 rows) x 1024 threads
// = 1 block/CU, 16 waves/CU.
// amdgpu_waves_per_eu(4,4): pin backend occupancy target to 4 waves/EU
// (= this kernel's own 16 waves), giving the FULL 128-VGPR budget. Without
// it the backend targeted 8 waves/EU (64 VGPR) and SPILLED the ~102-reg
// live set to scratch: round-7 counters showed +158 MB FETCH / +119 MB
// WRITE of pure spill traffic and a 2.5x slowdown.
// Decomposition (halves LDS-read traffic vs round 6):
//   thread: rs = tid>>7 (4 rows i0+4rs+rr), jg = tid&127 (j-groups jg, jg+128)
//   -> 320 B LDS read + 320 FMA per thread per iteration.
//   acc[4][10] = 40 VGPR; butterfly masks 1,2,4,8 -> 4 partials per wave
//   into vred[16][5][40] (strides 200/40 = 8 mod 32, conflict-free).
// Phase 0: base via relu-collapse, 32 cols/block == this tile's rows; base
//   stays in REGISTER b_reg (tid<320); emb0 = relu(base) -> eA (LLC stores).
// Iterations x4: stage whole-batch emb to LDS via sc0|sc1 bypass loads,
//   v = A@emb with A register-resident (loaded ONCE), out = relu(b_reg+v@Wp^T).
// Final: emb_out + q epilogue via qpart tree across one more per-batch barrier.
// ---------------------------------------------------------------------------
__global__ __launch_bounds__(1024, 4)
__attribute__((amdgpu_waves_per_eu(4, 4)))
void k_fused(
    const float* __restrict__ W, const float* __restrict__ features,
    const float* __restrict__ w_sel, const float* __restrict__ w_nbw,
    const float* __restrict__ w_ew, const float* __restrict__ A,
    const float* __restrict__ Wp, const float* __restrict__ w_reduc,
    const float* __restrict__ w_all, const float* __restrict__ w_act,
    float* eA, float* eB,
    float* __restrict__ emb_out, float* __restrict__ qv,
    float* __restrict__ qpart, unsigned* __restrict__ bars)
{
    __shared__ float4 EmS[EMB_F4];        // 45056 B (phase 0 overlays scratch)
    __shared__ float vred[16][5][4 * E];  // 12800 B (strides 200/40: 8 mod 32)
    __shared__ float WpS[E * E];
    __shared__ float gaS[E], gactS[E];
    __shared__ float vS[32 * E], qS[32 * E], qrow[32];
    __shared__ float qsumS;

    int bx = blockIdx.x, tid = threadIdx.x;
    int b = bx >> 5, tile = bx & 31;
    int i0 = tile * 32;
    int w = tid >> 6;     // wave 0..15
    int s = tid & 63;     // lane
    int rs = tid >> 7;    // row-set 0..7: rows i0 + 4*rs + rr
    int jg = tid & 127;   // j-group: j = 4*(jg + 128c) + q
    unsigned* mybars = bars + b * BAR_PAD;   // stage st: mybars[st * B * BAR_PAD]

    // ---- A tile (32 rows) -> registers, ONCE (8 coalesced float4/thread;
    //      latency hides under phase-0's W stream) ----
    float Arf[4][2][4];
    {
        const float* Ab = A + ((size_t)(b * N) + i0 + (rs << 2)) * N + 4 * jg;
#pragma unroll
        for (int rr = 0; rr < 4; ++rr)
#pragma unroll
            for (int c = 0; c < 2; ++c) {
                float4 t = *(const float4*)(Ab + (size_t)rr * N + 512 * c);
                Arf[rr][c][0] = t.x; Arf[rr][c][1] = t.y;
                Arf[rr][c][2] = t.z; Arf[rr][c][3] = t.w;
            }
    }

    if (tid < E * E) WpS[tid] = Wp[tid];
    if (tid < E) {
        float sa = 0.f, sc = 0.f;
#pragma unroll
        for (int k = 0; k < E; ++k) {
            sa += w_reduc[k] * w_all[k * E + tid];
            sc += w_reduc[E + k] * w_act[k * E + tid];
        }
        gaS[tid] = sa;
        gactS[tid] = sc;
    }

    // ---- phase 0: base + emb0 via relu-collapse, 32 cols/block ----
    float b_reg = 0.f;
    {
        float* redPt = (float*)&EmS[0];       // [32][129] transposed scratch
        float* redNt = redPt + 32 * 129;      // [32][129]
        float* scol  = redNt + 32 * 129;      // [2][32]
        int c4 = (tid & 7) * 4;               // float4 col group within 32 cols
        int rg = tid >> 3;                    // 128 row-groups x 8 rows
        const float* wp = W + ((size_t)b * N + rg * 8) * N + i0 + c4;
        float4 sp = {0.f, 0.f, 0.f, 0.f}, sn = {0.f, 0.f, 0.f, 0.f};
#pragma unroll
        for (int i = 0; i < 8; ++i) {
            float4 ww = *(const float4*)(wp + (size_t)i * N);
            sp.x += fmaxf(ww.x, 0.f); sn.x += fmaxf(-ww.x, 0.f);
            sp.y += fmaxf(ww.y, 0.f); sn.y += fmaxf(-ww.y, 0.f);
            sp.z += fmaxf(ww.z, 0.f); sn.z += fmaxf(-ww.z, 0.f);
            sp.w += fmaxf(ww.w, 0.f); sn.w += fmaxf(-ww.w, 0.f);
        }
        redPt[(c4 + 0) * 129 + rg] = sp.x; redNt[(c4 + 0) * 129 + rg] = sn.x;
        redPt[(c4 + 1) * 129 + rg] = sp.y; redNt[(c4 + 1) * 129 + rg] = sn.y;
        redPt[(c4 + 2) * 129 + rg] = sp.z; redNt[(c4 + 2) * 129 + rg] = sn.z;
        redPt[(c4 + 3) * 129 + rg] = sp.w; redNt[(c4 + 3) * 129 + rg] = sn.w;
        __syncthreads();
        if (tid < 64) {
            int cc = tid & 31;
            const float* rp = (tid < 32) ? redPt : redNt;
            float t = 0.f;
#pragma unroll 8
            for (int g = 0; g < 128; ++g) t += rp[cc * 129 + g];
            scol[(tid >> 5) * 32 + cc] = t;
        }
        __syncthreads();
        if (tid < 32 * E) {
            int cc = tid / E, f = tid % E;
            float spc = scol[cc], snc = scol[32 + cc];
            float acc = features[(b << 10) + i0 + cc] * w_sel[f];
#pragma unroll
            for (int e = 0; e < E; ++e) {
                float ce = w_ew[e];
                float se = (ce > 0.f) ? ce * spc : (-ce) * snc;
                acc += w_nbw[f * E + e] * se;
            }
            b_reg = acc;                       // base stays in register
            int row = i0 + cc;
            store_llc(&eA[(size_t)b * EMB_FLOATS + (row >> 2) * GP + (row & 3) * E + f],
                      fmaxf(acc, 0.f));        // emb after ref iter 1
        }
    }
    batch_barrier(&mybars[0]);

    // ---- 4 remaining reference iterations, A tile register-resident ----
    float da = 0.f;
    for (int it = 0; it < 4; ++it) {
        const float* ein = (it & 1) ? (const float*)eB : (const float*)eA;
        float* eout = (it & 1) ? eA : eB;

        // stage whole-batch emb: 3 LLC-bypass float4 loads/thread, ds_writes
        {
            const f32x4* src = (const f32x4*)ein + (size_t)b * EMB_F4;
            f32x4 t0, t1, t2 = {0.f, 0.f, 0.f, 0.f};
            asm volatile("global_load_dwordx4 %0, %1, off sc0 sc1"
                         : "=v"(t0) : "v"(src + tid) : "memory");
            asm volatile("global_load_dwordx4 %0, %1, off sc0 sc1"
                         : "=v"(t1) : "v"(src + tid + 1024) : "memory");
            if (tid < EMB_F4 - 2048)           // 768: waves 12-15 skip (uniform)
                asm volatile("global_load_dwordx4 %0, %1, off sc0 sc1"
                             : "=v"(t2) : "v"(src + tid + 2048) : "memory");
            asm volatile("s_waitcnt vmcnt(0)" ::: "memory");
            __builtin_amdgcn_sched_barrier(0);
            ((f32x4*)EmS)[tid]        = t0;
            ((f32x4*)EmS)[tid + 1024] = t1;
            if (tid < EMB_F4 - 2048) ((f32x4*)EmS)[tid + 2048] = t2;
        }
        __syncthreads();

        float acc[4][E];
#pragma unroll
        for (int rr = 0; rr < 4; ++rr)
#pragma unroll
            for (int e = 0; e < E; ++e) acc[rr][e] = 0.f;

#pragma unroll
        for (int c = 0; c < 2; ++c) {
            const float4* gp = EmS + (size_t)(jg + 128 * c) * (GP / 4);
            // first half of group: rows q=0,1 (floats 0..19)
            {
                float4 g4a[5];
#pragma unroll
                for (int t = 0; t < 5; ++t) g4a[t] = gp[t];
                const float* ga = (const float*)g4a;
#pragma unroll
                for (int q = 0; q < 2; ++q)
#pragma unroll
                    for (int rr = 0; rr < 4; ++rr) {
                        float a = Arf[rr][c][q];
#pragma unroll
                        for (int e = 0; e < E; ++e)
                            acc[rr][e] += a * ga[q * E + e];
                    }
            }
            // second half: rows q=2,3 (floats 20..39)
            {
                float4 g4b[5];
#pragma unroll
                for (int t = 0; t < 5; ++t) g4b[t] = gp[5 + t];
                const float* gb = (const float*)g4b;
#pragma unroll
                for (int q = 0; q < 2; ++q)
#pragma unroll
                    for (int rr = 0; rr < 4; ++rr) {
                        float a = Arf[rr][c][q + 2];
#pragma unroll
                        for (int e = 0; e < E; ++e)
                            acc[rr][e] += a * gb[q * E + e];
                    }
            }
        }

        // reduce 64 lanes -> 4 partials per wave (masks 1,2,4,8: DPP/VALU)
#pragma unroll
        for (int mask = 1; mask <= 8; mask <<= 1)
#pragma unroll
            for (int rr = 0; rr < 4; ++rr)
#pragma unroll
                for (int e = 0; e < E; ++e)
                    acc[rr][e] += __shfl_xor(acc[rr][e], mask, 64);
        if ((s & 15) == 0)
#pragma unroll
            for (int rr = 0; rr < 4; ++rr)
#pragma unroll
                for (int e = 0; e < E; ++e)
                    vred[w][s >> 4][rr * E + e] = acc[rr][e];
        __syncthreads();

        if (tid < 32 * E) {
            int r = tid / E, f = tid % E;
            int prs = r >> 2, rr = r & 3;
            float v[E];
#pragma unroll
            for (int e = 0; e < E; ++e) {
                float t = 0.f;
#pragma unroll
                for (int h = 0; h < 2; ++h)
#pragma unroll
                    for (int p = 0; p < 4; ++p)
                        t += vred[(prs << 1) + h][p][rr * E + e];
                v[e] = t;
            }
            float d = 0.f;
#pragma unroll
            for (int e = 0; e < E; ++e) d += v[e] * WpS[f * E + e];
            float r_out = fmaxf(b_reg + d, 0.f);
            if (it < 3) {
                int grow = i0 + r;
                store_llc(&eout[(size_t)b * EMB_FLOATS + (grow >> 2) * GP + (grow & 3) * E + f],
                          r_out);
            } else {
                size_t gi = (size_t)((b << 10) + i0 + r);
                emb_out[gi * E + f] = r_out;
                vS[tid] = r_out * gactS[f];
                qS[tid] = r_out * gaS[f];
            }
        }
        if (it < 3) batch_barrier(&mybars[(1 + it) * B * BAR_PAD]);
    }

    // ---- q epilogue: per-tile partials, one barrier, deterministic sum ----
    __syncthreads();
    if (tid < 32) {
        float dg = 0.f;
#pragma unroll
        for (int f = 0; f < E; ++f) {
            da += vS[tid * E + f];
            dg += qS[tid * E + f];
        }
        qrow[tid] = dg;
    }
    __syncthreads();
    if (tid == 0) {
        float t = 0.f;
#pragma unroll
        for (int r = 0; r < 32; ++r) t += qrow[r];
        store_llc(&qpart[bx], t);
    }
    batch_barrier(&mybars[4 * B * BAR_PAD]);

    if (tid < 32) {
        float t = load_llc(&qpart[(b << 5) + tid]);
#pragma unroll
        for (int mask = 1; mask < 32; mask <<= 1)
            t += __shfl_xor(t, mask, 32);
        if (tid == 0) qsumS = t;
    }
    __syncthreads();
    if (tid < 32) qv[(b << 10) + i0 + tid] = da + qsumS;
}

extern "C" void kernel_launch(void* const* d_in, const int* in_sizes, int n_in,
                              void* d_out, int out_size, void* d_ws, size_t ws_size,
                              hipStream_t stream) {
    const float* features  = (const float*)d_in[0];
    const float* W         = (const float*)d_in[1];
    const float* adjacency = (const float*)d_in[2];
    const float* w_sel     = (const float*)d_in[3];
    const float* w_pri     = (const float*)d_in[4];
    const float* w_nbw     = (const float*)d_in[5];
    const float* w_ew      = (const float*)d_in[6];
    const float* w_reduc   = (const float*)d_in[7];
    const float* w_all     = (const float*)d_in[8];
    const float* w_act     = (const float*)d_in[9];

    float* out     = (float*)d_out;
    float* qv      = out;              // B*N
    float* emb_out = out + B * N;      // B*N*E

    float* ws      = (float*)d_ws;
    float* eA      = ws;                               // B*EMB_FLOATS
    float* eB      = eA + (size_t)B * EMB_FLOATS;
    float* qpart   = eB + (size_t)B * EMB_FLOATS;      // 256 floats
    unsigned* bars = (unsigned*)(qpart + NBLK);        // 5 stages x 8 batches x 128B

    hipMemsetAsync(bars, 0, 5 * B * BAR_PAD * sizeof(unsigned), stream);
    k_fused<<<NBLK, 1024, 0, stream>>>(W, features, w_sel, w_nbw, w_ew,
                                       adjacency, w_pri, w_reduc, w_all, w_act,
                                       eA, eB, emb_out, qv, qpart, bars);
}

// Round 9
// 223.393 us; speedup vs baseline: 1.0220x; 1.0205x over previous
//
#include <hip/hip_runtime.h>

#define B 8
#define N 1024
#define E 10
#define GP 44                        // 4 emb rows packed in 44 floats (40 data + 4 pad)
#define EMB_FLOATS (256 * GP)        // 11264 floats per batch
#define EMB_F4 (EMB_FLOATS / 4)      // 2816 float4 per batch
#define EMS_PAD 1536                 // +24576 B: push LDS past 80KB so only ONE
                                     // 1024-thr block fits/CU -> backend occupancy
                                     // target drops to 4 waves/EU -> 128-VGPR
                                     // budget -> no spill (r7/r8: 64-VGPR target
                                     // for 2-block occupancy spilled 280 MB)
#define NBLK 256                     // 8 batches x 32 tiles of 32 rows
#define TPB 32                       // blocks per batch (barrier domain)
#define BAR_PAD 32                   // 32 uints = 128 B between counters

typedef float f32x4 __attribute__((ext_vector_type(4)));

// ---------------------------------------------------------------------------
// Fence-free PER-BATCH barrier (32 blocks). All cross-block data moves via
// sc0|sc1 write-through stores and sc0|sc1 bypass loads, so no buffer_wbl2 /
// buffer_inv is needed. __syncthreads() drains vmcnt(0) for every wave before
// s_barrier, so all write-through stores are LLC-visible before the counter
// increment. Each counter on its own 128 B line; batches fully decoupled.
// ---------------------------------------------------------------------------
__device__ __forceinline__ void batch_barrier(unsigned* cnt) {
    __syncthreads();   // s_waitcnt vmcnt(0) lgkmcnt(0) + s_barrier per wave
    if (threadIdx.x == 0) {
        __hip_atomic_fetch_add(cnt, 1u, __ATOMIC_RELAXED, __HIP_MEMORY_SCOPE_AGENT);
        while (__hip_atomic_load(cnt, __ATOMIC_RELAXED, __HIP_MEMORY_SCOPE_AGENT) < TPB)
            __builtin_amdgcn_s_sleep(2);
    }
    __syncthreads();
    asm volatile("" ::: "memory");   // compiler ordering only
}

// write-through to LLC (agent-visible once vmcnt drains)
__device__ __forceinline__ void store_llc(float* p, float v) {
    __hip_atomic_store((unsigned*)p, __float_as_uint(v),
                       __ATOMIC_RELAXED, __HIP_MEMORY_SCOPE_AGENT);
}
__device__ __forceinline__ float load_llc(const float* p) {
    unsigned u = __hip_atomic_load((const unsigned*)p,
                                   __ATOMIC_RELAXED, __HIP_MEMORY_SCOPE_AGENT);
    return __uint_as_float(u);
}

// ---------------------------------------------------------------------------
// Fully fused kernel. 256 blocks (8 b x 32 tiles of 32 rows) x 1024 threads
// = 1 block/CU, 16 waves/CU. EmS padded so LDS > 80KB: the register
// allocator's occupancy target is LDS-derived; at 61KB it assumed 2
// blocks/CU (8 waves/EU) and capped VGPR at 64, spilling the ~100-reg live
// set (r7/r8: +158 MB FETCH, +119 MB WRITE, 2.5x slowdown). At >80KB only
// 1 block fits -> 4 waves/EU target -> 128-VGPR budget, zero spill.
// Decomposition (halves LDS-read traffic vs round 6):
//   thread: rs = tid>>7 (4 rows i0+4rs+rr), jg = tid&127 (j-groups jg, jg+128)
//   -> 320 B LDS read + 320 FMA per thread per iteration.
//   acc[4][10] = 40 VGPR; butterfly masks 1,2,4,8 -> 4 partials per wave
//   into vred[16][5][40] (strides 200/40 = 8 mod 32, conflict-free).
// Phase 0: base via relu-collapse, 32 cols/block == this tile's rows; base
//   stays in REGISTER b_reg (tid<320); emb0 = relu(base) -> eA (LLC stores).
// Iterations x4: stage whole-batch emb to LDS via sc0|sc1 bypass loads,
//   v = A@emb with A register-resident (loaded ONCE), out = relu(b_reg+v@Wp^T).
// Final: emb_out + q epilogue via qpart tree across one more per-batch barrier.
// ---------------------------------------------------------------------------
__global__ __launch_bounds__(1024, 4)
void k_fused(
    const float* __restrict__ W, const float* __restrict__ features,
    const float* __restrict__ w_sel, const float* __restrict__ w_nbw,
    const float* __restrict__ w_ew, const float* __restrict__ A,
    const float* __restrict__ Wp, const float* __restrict__ w_reduc,
    const float* __restrict__ w_all, const float* __restrict__ w_act,
    float* eA, float* eB,
    float* __restrict__ emb_out, float* __restrict__ qv,
    float* __restrict__ qpart, unsigned* __restrict__ bars)
{
    __shared__ float4 EmS[EMB_F4 + EMS_PAD];  // 69632 B (pad forces 1 blk/CU)
    __shared__ float vred[16][5][4 * E];  // 12800 B (strides 200/40: 8 mod 32)
    __shared__ float WpS[E * E];
    __shared__ float gaS[E], gactS[E];
    __shared__ float vS[32 * E], qS[32 * E], qrow[32];
    __shared__ float qsumS;

    int bx = blockIdx.x, tid = threadIdx.x;
    int b = bx >> 5, tile = bx & 31;
    int i0 = tile * 32;
    int w = tid >> 6;     // wave 0..15
    int s = tid & 63;     // lane
    int rs = tid >> 7;    // row-set 0..7: rows i0 + 4*rs + rr
    int jg = tid & 127;   // j-group: j = 4*(jg + 128c) + q
    unsigned* mybars = bars + b * BAR_PAD;   // stage st: mybars[st * B * BAR_PAD]

    // ---- A tile (32 rows) -> registers, ONCE (8 coalesced float4/thread;
    //      latency hides under phase-0's W stream) ----
    float Arf[4][2][4];
    {
        const float* Ab = A + ((size_t)(b * N) + i0 + (rs << 2)) * N + 4 * jg;
#pragma unroll
        for (int rr = 0; rr < 4; ++rr)
#pragma unroll
            for (int c = 0; c < 2; ++c) {
                float4 t = *(const float4*)(Ab + (size_t)rr * N + 512 * c);
                Arf[rr][c][0] = t.x; Arf[rr][c][1] = t.y;
                Arf[rr][c][2] = t.z; Arf[rr][c][3] = t.w;
            }
    }

    if (tid < E * E) WpS[tid] = Wp[tid];
    if (tid < E) {
        float sa = 0.f, sc = 0.f;
#pragma unroll
        for (int k = 0; k < E; ++k) {
            sa += w_reduc[k] * w_all[k * E + tid];
            sc += w_reduc[E + k] * w_act[k * E + tid];
        }
        gaS[tid] = sa;
        gactS[tid] = sc;
    }

    // ---- phase 0: base + emb0 via relu-collapse, 32 cols/block ----
    float b_reg = 0.f;
    {
        float* redPt = (float*)&EmS[0];       // [32][129] transposed scratch
        float* redNt = redPt + 32 * 129;      // [32][129]
        float* scol  = redNt + 32 * 129;      // [2][32]
        int c4 = (tid & 7) * 4;               // float4 col group within 32 cols
        int rg = tid >> 3;                    // 128 row-groups x 8 rows
        const float* wp = W + ((size_t)b * N + rg * 8) * N + i0 + c4;
        float4 sp = {0.f, 0.f, 0.f, 0.f}, sn = {0.f, 0.f, 0.f, 0.f};
#pragma unroll
        for (int i = 0; i < 8; ++i) {
            float4 ww = *(const float4*)(wp + (size_t)i * N);
            sp.x += fmaxf(ww.x, 0.f); sn.x += fmaxf(-ww.x, 0.f);
            sp.y += fmaxf(ww.y, 0.f); sn.y += fmaxf(-ww.y, 0.f);
            sp.z += fmaxf(ww.z, 0.f); sn.z += fmaxf(-ww.z, 0.f);
            sp.w += fmaxf(ww.w, 0.f); sn.w += fmaxf(-ww.w, 0.f);
        }
        redPt[(c4 + 0) * 129 + rg] = sp.x; redNt[(c4 + 0) * 129 + rg] = sn.x;
        redPt[(c4 + 1) * 129 + rg] = sp.y; redNt[(c4 + 1) * 129 + rg] = sn.y;
        redPt[(c4 + 2) * 129 + rg] = sp.z; redNt[(c4 + 2) * 129 + rg] = sn.z;
        redPt[(c4 + 3) * 129 + rg] = sp.w; redNt[(c4 + 3) * 129 + rg] = sn.w;
        __syncthreads();
        if (tid < 64) {
            int cc = tid & 31;
            const float* rp = (tid < 32) ? redPt : redNt;
            float t = 0.f;
#pragma unroll 8
            for (int g = 0; g < 128; ++g) t += rp[cc * 129 + g];
            scol[(tid >> 5) * 32 + cc] = t;
        }
        __syncthreads();
        if (tid < 32 * E) {
            int cc = tid / E, f = tid % E;
            float spc = scol[cc], snc = scol[32 + cc];
            float acc = features[(b << 10) + i0 + cc] * w_sel[f];
#pragma unroll
            for (int e = 0; e < E; ++e) {
                float ce = w_ew[e];
                float se = (ce > 0.f) ? ce * spc : (-ce) * snc;
                acc += w_nbw[f * E + e] * se;
            }
            b_reg = acc;                       // base stays in register
            int row = i0 + cc;
            store_llc(&eA[(size_t)b * EMB_FLOATS + (row >> 2) * GP + (row & 3) * E + f],
                      fmaxf(acc, 0.f));        // emb after ref iter 1
        }
    }
    batch_barrier(&mybars[0]);

    // ---- 4 remaining reference iterations, A tile register-resident ----
    float da = 0.f;
    for (int it = 0; it < 4; ++it) {
        const float* ein = (it & 1) ? (const float*)eB : (const float*)eA;
        float* eout = (it & 1) ? eA : eB;

        // stage whole-batch emb: 3 LLC-bypass float4 loads/thread, ds_writes
        {
            const f32x4* src = (const f32x4*)ein + (size_t)b * EMB_F4;
            f32x4 t0, t1, t2 = {0.f, 0.f, 0.f, 0.f};
            asm volatile("global_load_dwordx4 %0, %1, off sc0 sc1"
                         : "=v"(t0) : "v"(src + tid) : "memory");
            asm volatile("global_load_dwordx4 %0, %1, off sc0 sc1"
                         : "=v"(t1) : "v"(src + tid + 1024) : "memory");
            if (tid < EMB_F4 - 2048)           // 768: waves 12-15 skip (uniform)
                asm volatile("global_load_dwordx4 %0, %1, off sc0 sc1"
                             : "=v"(t2) : "v"(src + tid + 2048) : "memory");
            asm volatile("s_waitcnt vmcnt(0)" ::: "memory");
            __builtin_amdgcn_sched_barrier(0);
            ((f32x4*)EmS)[tid]        = t0;
            ((f32x4*)EmS)[tid + 1024] = t1;
            if (tid < EMB_F4 - 2048) ((f32x4*)EmS)[tid + 2048] = t2;
        }
        __syncthreads();

        float acc[4][E];
#pragma unroll
        for (int rr = 0; rr < 4; ++rr)
#pragma unroll
            for (int e = 0; e < E; ++e) acc[rr][e] = 0.f;

#pragma unroll
        for (int c = 0; c < 2; ++c) {
            const float4* gp = EmS + (size_t)(jg + 128 * c) * (GP / 4);
            // first half of group: rows q=0,1 (floats 0..19)
            {
                float4 g4a[5];
#pragma unroll
                for (int t = 0; t < 5; ++t) g4a[t] = gp[t];
                const float* ga = (const float*)g4a;
#pragma unroll
                for (int q = 0; q < 2; ++q)
#pragma unroll
                    for (int rr = 0; rr < 4; ++rr) {
                        float a = Arf[rr][c][q];
#pragma unroll
                        for (int e = 0; e < E; ++e)
                            acc[rr][e] += a * ga[q * E + e];
                    }
            }
            // second half: rows q=2,3 (floats 20..39)
            {
                float4 g4b[5];
#pragma unroll
                for (int t = 0; t < 5; ++t) g4b[t] = gp[5 + t];
                const float* gb = (const float*)g4b;
#pragma unroll
                for (int q = 0; q < 2; ++q)
#pragma unroll
                    for (int rr = 0; rr < 4; ++rr) {
                        float a = Arf[rr][c][q + 2];
#pragma unroll
                        for (int e = 0; e < E; ++e)
                            acc[rr][e] += a * gb[q * E + e];
                    }
            }
        }

        // reduce 64 lanes -> 4 partials per wave (masks 1,2,4,8: DPP/VALU)
#pragma unroll
        for (int mask = 1; mask <= 8; mask <<= 1)
#pragma unroll
            for (int rr = 0; rr < 4; ++rr)
#pragma unroll
                for (int e = 0; e < E; ++e)
                    acc[rr][e] += __shfl_xor(acc[rr][e], mask, 64);
        if ((s & 15) == 0)
#pragma unroll
            for (int rr = 0; rr < 4; ++rr)
#pragma unroll
                for (int e = 0; e < E; ++e)
                    vred[w][s >> 4][rr * E + e] = acc[rr][e];
        __syncthreads();

        if (tid < 32 * E) {
            int r = tid / E, f = tid % E;
            int prs = r >> 2, rr = r & 3;
            float v[E];
#pragma unroll
            for (int e = 0; e < E; ++e) {
                float t = 0.f;
#pragma unroll
                for (int h = 0; h < 2; ++h)
#pragma unroll
                    for (int p = 0; p < 4; ++p)
                        t += vred[(prs << 1) + h][p][rr * E + e];
                v[e] = t;
            }
            float d = 0.f;
#pragma unroll
            for (int e = 0; e < E; ++e) d += v[e] * WpS[f * E + e];
            float r_out = fmaxf(b_reg + d, 0.f);
            if (it < 3) {
                int grow = i0 + r;
                store_llc(&eout[(size_t)b * EMB_FLOATS + (grow >> 2) * GP + (grow & 3) * E + f],
                          r_out);
            } else {
                size_t gi = (size_t)((b << 10) + i0 + r);
                emb_out[gi * E + f] = r_out;
                vS[tid] = r_out * gactS[f];
                qS[tid] = r_out * gaS[f];
            }
        }
        if (it < 3) batch_barrier(&mybars[(1 + it) * B * BAR_PAD]);
    }

    // ---- q epilogue: per-tile partials, one barrier, deterministic sum ----
    __syncthreads();
    if (tid < 32) {
        float dg = 0.f;
#pragma unroll
        for (int f = 0; f < E; ++f) {
            da += vS[tid * E + f];
            dg += qS[tid * E + f];
        }
        qrow[tid] = dg;
    }
    __syncthreads();
    if (tid == 0) {
        float t = 0.f;
#pragma unroll
        for (int r = 0; r < 32; ++r) t += qrow[r];
        store_llc(&qpart[bx], t);
    }
    batch_barrier(&mybars[4 * B * BAR_PAD]);

    if (tid < 32) {
        float t = load_llc(&qpart[(b << 5) + tid]);
#pragma unroll
        for (int mask = 1; mask < 32; mask <<= 1)
            t += __shfl_xor(t, mask, 32);
        if (tid == 0) qsumS = t;
    }
    __syncthreads();
    if (tid < 32) qv[(b << 10) + i0 + tid] = da + qsumS;
}

extern "C" void kernel_launch(void* const* d_in, const int* in_sizes, int n_in,
                              void* d_out, int out_size, void* d_ws, size_t ws_size,
                              hipStream_t stream) {
    const float* features  = (const float*)d_in[0];
    const float* W         = (const float*)d_in[1];
    const float* adjacency = (const float*)d_in[2];
    const float* w_sel     = (const float*)d_in[3];
    const float* w_pri     = (const float*)d_in[4];
    const float* w_nbw     = (const float*)d_in[5];
    const float* w_ew      = (const float*)d_in[6];
    const float* w_reduc   = (const float*)d_in[7];
    const float* w_all     = (const float*)d_in[8];
    const float* w_act     = (const float*)d_in[9];

    float* out     = (float*)d_out;
    float* qv      = out;              // B*N
    float* emb_out = out + B * N;      // B*N*E

    float* ws      = (float*)d_ws;
    float* eA      = ws;                               // B*EMB_FLOATS
    float* eB      = eA + (size_t)B * EMB_FLOATS;
    float* qpart   = eB + (size_t)B * EMB_FLOATS;      // 256 floats
    unsigned* bars = (unsigned*)(qpart + NBLK);        // 5 stages x 8 batches x 128B

    hipMemsetAsync(bars, 0, 5 * B * BAR_PAD * sizeof(unsigned), stream);
    k_fused<<<NBLK, 1024, 0, stream>>>(W, features, w_sel, w_nbw, w_ew,
                                       adjacency, w_pri, w_reduc, w_all, w_act,
                                       eA, eB, emb_out, qv, qpart, bars);
}

// Round 10
// 146.760 us; speedup vs baseline: 1.5557x; 1.5222x over previous
//
#include <hip/hip_runtime.h>

#define B 8
#define N 1024
#define E 10
#define GP 44                        // 4 emb rows packed in 44 floats (40 data + 4 pad)
#define EMB_FLOATS (256 * GP)        // 11264 floats per batch
#define EMB_F4 (EMB_FLOATS / 4)     // 2816 float4 per batch
#define NBLK 256                     // 8 batches x 32 tiles of 32 rows
#define TPB 32                       // blocks per batch (barrier domain)
#define BAR_PAD 32                   // 32 uints = 128 B between counters

typedef float f32x4 __attribute__((ext_vector_type(4)));

// ---------------------------------------------------------------------------
// Fence-free PER-BATCH barrier (32 blocks). All cross-block data moves via
// sc0|sc1 write-through stores and sc0|sc1 bypass loads, so no buffer_wbl2 /
// buffer_inv is needed. __syncthreads() drains vmcnt(0) for every wave before
// s_barrier, so all write-through stores are LLC-visible before the counter
// increment. Each counter on its own 128 B line; batches fully decoupled.
// ---------------------------------------------------------------------------
__device__ __forceinline__ void batch_barrier(unsigned* cnt) {
    __syncthreads();
    if (threadIdx.x == 0) {
        __hip_atomic_fetch_add(cnt, 1u, __ATOMIC_RELAXED, __HIP_MEMORY_SCOPE_AGENT);
        while (__hip_atomic_load(cnt, __ATOMIC_RELAXED, __HIP_MEMORY_SCOPE_AGENT) < TPB)
            __builtin_amdgcn_s_sleep(2);
    }
    __syncthreads();
    asm volatile("" ::: "memory");
}

__device__ __forceinline__ void store_llc(float* p, float v) {
    __hip_atomic_store((unsigned*)p, __float_as_uint(v),
                       __ATOMIC_RELAXED, __HIP_MEMORY_SCOPE_AGENT);
}
__device__ __forceinline__ float load_llc(const float* p) {
    unsigned u = __hip_atomic_load((const unsigned*)p,
                                   __ATOMIC_RELAXED, __HIP_MEMORY_SCOPE_AGENT);
    return __uint_as_float(u);
}

// ===========================================================================
// Shared phase-0 + epilogue structure; two variants of the iteration
// decomposition. k6 = round-6 proven kernel (fits 64-VGPR budget, 53.5us).
// k7 = R=4 decomposition (needs ~100 VGPR; ONLY correct-speed if the
// allocator honors amdgpu_waves_per_eu(4,4) and allocates >=96 without
// scratch). kernel_launch picks at runtime via hipFuncGetAttributes:
// localSizeBytes==0 && numRegs>=96 -> k7, else k6. r7-r9 showed
// __launch_bounds__(1024,4)'s min-only waves-per-eu lets the backend target
// 8 waves/EU (64 VGPR) and spill 280 MB; k7 drops __launch_bounds__ entirely
// in favor of explicit flat_work_group_size + waves_per_eu(min=max=4).
// ===========================================================================

// --------------------------- k6 (round-6 exact) ----------------------------
__global__ __launch_bounds__(1024, 4)
void k_fused6(
    const float* __restrict__ W, const float* __restrict__ features,
    const float* __restrict__ w_sel, const float* __restrict__ w_nbw,
    const float* __restrict__ w_ew, const float* __restrict__ A,
    const float* __restrict__ Wp, const float* __restrict__ w_reduc,
    const float* __restrict__ w_all, const float* __restrict__ w_act,
    float* eA, float* eB,
    float* __restrict__ emb_out, float* __restrict__ qv,
    float* __restrict__ qpart, unsigned* __restrict__ bars)
{
    __shared__ float4 EmS[EMB_F4];
    __shared__ float vred[16][9][2 * E];
    __shared__ float WpS[E * E];
    __shared__ float gaS[E], gactS[E];
    __shared__ float vS[32 * E], qS[32 * E], qrow[32];
    __shared__ float qsumS;

    int bx = blockIdx.x, tid = threadIdx.x;
    int b = bx >> 5, tile = bx & 31;
    int i0 = tile * 32;
    int m = tid >> 6;     // wave 0..15: rows i0 + m + 16k
    int s = tid & 63;     // lane: cols 4s + q + 256c
    unsigned* mybars = bars + b * BAR_PAD;

    float Arf[2][4][4];
    {
        const float* Ab = A + ((size_t)(b * N) + i0 + m) * N + 4 * s;
#pragma unroll
        for (int k = 0; k < 2; ++k)
#pragma unroll
            for (int c = 0; c < 4; ++c) {
                float4 t = *(const float4*)(Ab + (size_t)(16 * k) * N + 256 * c);
                Arf[k][c][0] = t.x; Arf[k][c][1] = t.y;
                Arf[k][c][2] = t.z; Arf[k][c][3] = t.w;
            }
    }

    if (tid < E * E) WpS[tid] = Wp[tid];
    if (tid < E) {
        float sa = 0.f, sc = 0.f;
#pragma unroll
        for (int k = 0; k < E; ++k) {
            sa += w_reduc[k] * w_all[k * E + tid];
            sc += w_reduc[E + k] * w_act[k * E + tid];
        }
        gaS[tid] = sa;
        gactS[tid] = sc;
    }

    float b_reg = 0.f;
    {
        float* redPt = (float*)&EmS[0];
        float* redNt = redPt + 32 * 129;
        float* scol  = redNt + 32 * 129;
        int c4 = (tid & 7) * 4;
        int rg = tid >> 3;
        const float* wp = W + ((size_t)b * N + rg * 8) * N + i0 + c4;
        float4 sp = {0.f, 0.f, 0.f, 0.f}, sn = {0.f, 0.f, 0.f, 0.f};
#pragma unroll
        for (int i = 0; i < 8; ++i) {
            float4 ww = *(const float4*)(wp + (size_t)i * N);
            sp.x += fmaxf(ww.x, 0.f); sn.x += fmaxf(-ww.x, 0.f);
            sp.y += fmaxf(ww.y, 0.f); sn.y += fmaxf(-ww.y, 0.f);
            sp.z += fmaxf(ww.z, 0.f); sn.z += fmaxf(-ww.z, 0.f);
            sp.w += fmaxf(ww.w, 0.f); sn.w += fmaxf(-ww.w, 0.f);
        }
        redPt[(c4 + 0) * 129 + rg] = sp.x; redNt[(c4 + 0) * 129 + rg] = sn.x;
        redPt[(c4 + 1) * 129 + rg] = sp.y; redNt[(c4 + 1) * 129 + rg] = sn.y;
        redPt[(c4 + 2) * 129 + rg] = sp.z; redNt[(c4 + 2) * 129 + rg] = sn.z;
        redPt[(c4 + 3) * 129 + rg] = sp.w; redNt[(c4 + 3) * 129 + rg] = sn.w;
        __syncthreads();
        if (tid < 64) {
            int cc = tid & 31;
            const float* rp = (tid < 32) ? redPt : redNt;
            float t = 0.f;
#pragma unroll 8
            for (int g = 0; g < 128; ++g) t += rp[cc * 129 + g];
            scol[(tid >> 5) * 32 + cc] = t;
        }
        __syncthreads();
        if (tid < 32 * E) {
            int cc = tid / E, f = tid % E;
            float spc = scol[cc], snc = scol[32 + cc];
            float acc = features[(b << 10) + i0 + cc] * w_sel[f];
#pragma unroll
            for (int e = 0; e < E; ++e) {
                float ce = w_ew[e];
                float se = (ce > 0.f) ? ce * spc : (-ce) * snc;
                acc += w_nbw[f * E + e] * se;
            }
            b_reg = acc;
            int row = i0 + cc;
            store_llc(&eA[(size_t)b * EMB_FLOATS + (row >> 2) * GP + (row & 3) * E + f],
                      fmaxf(acc, 0.f));
        }
    }
    batch_barrier(&mybars[0]);

    float da = 0.f;
    for (int it = 0; it < 4; ++it) {
        const float* ein = (it & 1) ? (const float*)eB : (const float*)eA;
        float* eout = (it & 1) ? eA : eB;

        {
            const f32x4* src = (const f32x4*)ein + (size_t)b * EMB_F4;
            f32x4 t0, t1, t2 = {0.f, 0.f, 0.f, 0.f};
            asm volatile("global_load_dwordx4 %0, %1, off sc0 sc1"
                         : "=v"(t0) : "v"(src + tid) : "memory");
            asm volatile("global_load_dwordx4 %0, %1, off sc0 sc1"
                         : "=v"(t1) : "v"(src + tid + 1024) : "memory");
            if (tid < EMB_F4 - 2048)
                asm volatile("global_load_dwordx4 %0, %1, off sc0 sc1"
                             : "=v"(t2) : "v"(src + tid + 2048) : "memory");
            asm volatile("s_waitcnt vmcnt(0)" ::: "memory");
            __builtin_amdgcn_sched_barrier(0);
            ((f32x4*)EmS)[tid]        = t0;
            ((f32x4*)EmS)[tid + 1024] = t1;
            if (tid < EMB_F4 - 2048) ((f32x4*)EmS)[tid + 2048] = t2;
        }
        __syncthreads();

        float acc[2][E];
#pragma unroll
        for (int k = 0; k < 2; ++k)
#pragma unroll
            for (int e = 0; e < E; ++e) acc[k][e] = 0.f;

#pragma unroll
        for (int c = 0; c < 4; ++c) {
            float4 g4[10];
            const float4* gp = EmS + (size_t)(s + 64 * c) * (GP / 4);
#pragma unroll
            for (int t = 0; t < 10; ++t) g4[t] = gp[t];
            const float* g40 = (const float*)g4;
#pragma unroll
            for (int q = 0; q < 4; ++q)
#pragma unroll
                for (int k = 0; k < 2; ++k) {
                    float a = Arf[k][c][q];
#pragma unroll
                    for (int e = 0; e < E; ++e)
                        acc[k][e] += a * g40[q * E + e];
                }
        }

#pragma unroll
        for (int mask = 1; mask <= 4; mask <<= 1)
#pragma unroll
            for (int k = 0; k < 2; ++k)
#pragma unroll
                for (int e = 0; e < E; ++e)
                    acc[k][e] += __shfl_xor(acc[k][e], mask, 64);
        if ((s & 7) == 0)
#pragma unroll
            for (int k = 0; k < 2; ++k)
#pragma unroll
                for (int e = 0; e < E; ++e)
                    vred[m][s >> 3][k * E + e] = acc[k][e];
        __syncthreads();

        if (tid < 32 * E) {
            int r = tid / E, f = tid % E;
            int mm = r & 15, kk = r >> 4;
            float v[E];
#pragma unroll
            for (int e = 0; e < E; ++e) {
                float t = 0.f;
#pragma unroll
                for (int g = 0; g < 8; ++g) t += vred[mm][g][kk * E + e];
                v[e] = t;
            }
            float d = 0.f;
#pragma unroll
            for (int e = 0; e < E; ++e) d += v[e] * WpS[f * E + e];
            float r_out = fmaxf(b_reg + d, 0.f);
            if (it < 3) {
                int grow = i0 + r;
                store_llc(&eout[(size_t)b * EMB_FLOATS + (grow >> 2) * GP + (grow & 3) * E + f],
                          r_out);
            } else {
                size_t gi = (size_t)((b << 10) + i0 + r);
                emb_out[gi * E + f] = r_out;
                vS[tid] = r_out * gactS[f];
                qS[tid] = r_out * gaS[f];
            }
        }
        if (it < 3) batch_barrier(&mybars[(1 + it) * B * BAR_PAD]);
    }

    __syncthreads();
    if (tid < 32) {
        float dg = 0.f;
#pragma unroll
        for (int f = 0; f < E; ++f) {
            da += vS[tid * E + f];
            dg += qS[tid * E + f];
        }
        qrow[tid] = dg;
    }
    __syncthreads();
    if (tid == 0) {
        float t = 0.f;
#pragma unroll
        for (int r = 0; r < 32; ++r) t += qrow[r];
        store_llc(&qpart[bx], t);
    }
    batch_barrier(&mybars[4 * B * BAR_PAD]);

    if (tid < 32) {
        float t = load_llc(&qpart[(b << 5) + tid]);
#pragma unroll
        for (int mask = 1; mask < 32; mask <<= 1)
            t += __shfl_xor(t, mask, 32);
        if (tid == 0) qsumS = t;
    }
    __syncthreads();
    if (tid < 32) qv[(b << 10) + i0 + tid] = da + qsumS;
}

// ------------------- k7 (R=4 decomposition, pinned waves) -------------------
__global__
__attribute__((amdgpu_flat_work_group_size(1024, 1024)))
__attribute__((amdgpu_waves_per_eu(4, 4)))
void k_fused7(
    const float* __restrict__ W, const float* __restrict__ features,
    const float* __restrict__ w_sel, const float* __restrict__ w_nbw,
    const float* __restrict__ w_ew, const float* __restrict__ A,
    const float* __restrict__ Wp, const float* __restrict__ w_reduc,
    const float* __restrict__ w_all, const float* __restrict__ w_act,
    float* eA, float* eB,
    float* __restrict__ emb_out, float* __restrict__ qv,
    float* __restrict__ qpart, unsigned* __restrict__ bars)
{
    __shared__ float4 EmS[EMB_F4];
    __shared__ float vred[16][5][4 * E];
    __shared__ float WpS[E * E];
    __shared__ float gaS[E], gactS[E];
    __shared__ float vS[32 * E], qS[32 * E], qrow[32];
    __shared__ float qsumS;

    int bx = blockIdx.x, tid = threadIdx.x;
    int b = bx >> 5, tile = bx & 31;
    int i0 = tile * 32;
    int w = tid >> 6;
    int s = tid & 63;
    int rs = tid >> 7;    // rows i0 + 4rs + rr
    int jg = tid & 127;   // j = 4*(jg + 128c) + q
    unsigned* mybars = bars + b * BAR_PAD;

    float Arf[4][2][4];
    {
        const float* Ab = A + ((size_t)(b * N) + i0 + (rs << 2)) * N + 4 * jg;
#pragma unroll
        for (int rr = 0; rr < 4; ++rr)
#pragma unroll
            for (int c = 0; c < 2; ++c) {
                float4 t = *(const float4*)(Ab + (size_t)rr * N + 512 * c);
                Arf[rr][c][0] = t.x; Arf[rr][c][1] = t.y;
                Arf[rr][c][2] = t.z; Arf[rr][c][3] = t.w;
            }
    }

    if (tid < E * E) WpS[tid] = Wp[tid];
    if (tid < E) {
        float sa = 0.f, sc = 0.f;
#pragma unroll
        for (int k = 0; k < E; ++k) {
            sa += w_reduc[k] * w_all[k * E + tid];
            sc += w_reduc[E + k] * w_act[k * E + tid];
        }
        gaS[tid] = sa;
        gactS[tid] = sc;
    }

    float b_reg = 0.f;
    {
        float* redPt = (float*)&EmS[0];
        float* redNt = redPt + 32 * 129;
        float* scol  = redNt + 32 * 129;
        int c4 = (tid & 7) * 4;
        int rg = tid >> 3;
        const float* wp = W + ((size_t)b * N + rg * 8) * N + i0 + c4;
        float4 sp = {0.f, 0.f, 0.f, 0.f}, sn = {0.f, 0.f, 0.f, 0.f};
#pragma unroll
        for (int i = 0; i < 8; ++i) {
            float4 ww = *(const float4*)(wp + (size_t)i * N);
            sp.x += fmaxf(ww.x, 0.f); sn.x += fmaxf(-ww.x, 0.f);
            sp.y += fmaxf(ww.y, 0.f); sn.y += fmaxf(-ww.y, 0.f);
            sp.z += fmaxf(ww.z, 0.f); sn.z += fmaxf(-ww.z, 0.f);
            sp.w += fmaxf(ww.w, 0.f); sn.w += fmaxf(-ww.w, 0.f);
        }
        redPt[(c4 + 0) * 129 + rg] = sp.x; redNt[(c4 + 0) * 129 + rg] = sn.x;
        redPt[(c4 + 1) * 129 + rg] = sp.y; redNt[(c4 + 1) * 129 + rg] = sn.y;
        redPt[(c4 + 2) * 129 + rg] = sp.z; redNt[(c4 + 2) * 129 + rg] = sn.z;
        redPt[(c4 + 3) * 129 + rg] = sp.w; redNt[(c4 + 3) * 129 + rg] = sn.w;
        __syncthreads();
        if (tid < 64) {
            int cc = tid & 31;
            const float* rp = (tid < 32) ? redPt : redNt;
            float t = 0.f;
#pragma unroll 8
            for (int g = 0; g < 128; ++g) t += rp[cc * 129 + g];
            scol[(tid >> 5) * 32 + cc] = t;
        }
        __syncthreads();
        if (tid < 32 * E) {
            int cc = tid / E, f = tid % E;
            float spc = scol[cc], snc = scol[32 + cc];
            float acc = features[(b << 10) + i0 + cc] * w_sel[f];
#pragma unroll
            for (int e = 0; e < E; ++e) {
                float ce = w_ew[e];
                float se = (ce > 0.f) ? ce * spc : (-ce) * snc;
                acc += w_nbw[f * E + e] * se;
            }
            b_reg = acc;
            int row = i0 + cc;
            store_llc(&eA[(size_t)b * EMB_FLOATS + (row >> 2) * GP + (row & 3) * E + f],
                      fmaxf(acc, 0.f));
        }
    }
    batch_barrier(&mybars[0]);

    float da = 0.f;
    for (int it = 0; it < 4; ++it) {
        const float* ein = (it & 1) ? (const float*)eB : (const float*)eA;
        float* eout = (it & 1) ? eA : eB;

        {
            const f32x4* src = (const f32x4*)ein + (size_t)b * EMB_F4;
            f32x4 t0, t1, t2 = {0.f, 0.f, 0.f, 0.f};
            asm volatile("global_load_dwordx4 %0, %1, off sc0 sc1"
                         : "=v"(t0) : "v"(src + tid) : "memory");
            asm volatile("global_load_dwordx4 %0, %1, off sc0 sc1"
                         : "=v"(t1) : "v"(src + tid + 1024) : "memory");
            if (tid < EMB_F4 - 2048)
                asm volatile("global_load_dwordx4 %0, %1, off sc0 sc1"
                             : "=v"(t2) : "v"(src + tid + 2048) : "memory");
            asm volatile("s_waitcnt vmcnt(0)" ::: "memory");
            __builtin_amdgcn_sched_barrier(0);
            ((f32x4*)EmS)[tid]        = t0;
            ((f32x4*)EmS)[tid + 1024] = t1;
            if (tid < EMB_F4 - 2048) ((f32x4*)EmS)[tid + 2048] = t2;
        }
        __syncthreads();

        float acc[4][E];
#pragma unroll
        for (int rr = 0; rr < 4; ++rr)
#pragma unroll
            for (int e = 0; e < E; ++e) acc[rr][e] = 0.f;

#pragma unroll
        for (int c = 0; c < 2; ++c) {
            const float4* gp = EmS + (size_t)(jg + 128 * c) * (GP / 4);
            {
                float4 g4a[5];
#pragma unroll
                for (int t = 0; t < 5; ++t) g4a[t] = gp[t];
                const float* ga = (const float*)g4a;
#pragma unroll
                for (int q = 0; q < 2; ++q)
#pragma unroll
                    for (int rr = 0; rr < 4; ++rr) {
                        float a = Arf[rr][c][q];
#pragma unroll
                        for (int e = 0; e < E; ++e)
                            acc[rr][e] += a * ga[q * E + e];
                    }
            }
            {
                float4 g4b[5];
#pragma unroll
                for (int t = 0; t < 5; ++t) g4b[t] = gp[5 + t];
                const float* gb = (const float*)g4b;
#pragma unroll
                for (int q = 0; q < 2; ++q)
#pragma unroll
                    for (int rr = 0; rr < 4; ++rr) {
                        float a = Arf[rr][c][q + 2];
#pragma unroll
                        for (int e = 0; e < E; ++e)
                            acc[rr][e] += a * gb[q * E + e];
                    }
            }
        }

#pragma unroll
        for (int mask = 1; mask <= 8; mask <<= 1)
#pragma unroll
            for (int rr = 0; rr < 4; ++rr)
#pragma unroll
                for (int e = 0; e < E; ++e)
                    acc[rr][e] += __shfl_xor(acc[rr][e], mask, 64);
        if ((s & 15) == 0)
#pragma unroll
            for (int rr = 0; rr < 4; ++rr)
#pragma unroll
                for (int e = 0; e < E; ++e)
                    vred[w][s >> 4][rr * E + e] = acc[rr][e];
        __syncthreads();

        if (tid < 32 * E) {
            int r = tid / E, f = tid % E;
            int prs = r >> 2, rr = r & 3;
            float v[E];
#pragma unroll
            for (int e = 0; e < E; ++e) {
                float t = 0.f;
#pragma unroll
                for (int h = 0; h < 2; ++h)
#pragma unroll
                    for (int p = 0; p < 4; ++p)
                        t += vred[(prs << 1) + h][p][rr * E + e];
                v[e] = t;
            }
            float d = 0.f;
#pragma unroll
            for (int e = 0; e < E; ++e) d += v[e] * WpS[f * E + e];
            float r_out = fmaxf(b_reg + d, 0.f);
            if (it < 3) {
                int grow = i0 + r;
                store_llc(&eout[(size_t)b * EMB_FLOATS + (grow >> 2) * GP + (grow & 3) * E + f],
                          r_out);
            } else {
                size_t gi = (size_t)((b << 10) + i0 + r);
                emb_out[gi * E + f] = r_out;
                vS[tid] = r_out * gactS[f];
                qS[tid] = r_out * gaS[f];
            }
        }
        if (it < 3) batch_barrier(&mybars[(1 + it) * B * BAR_PAD]);
    }

    __syncthreads();
    if (tid < 32) {
        float dg = 0.f;
#pragma unroll
        for (int f = 0; f < E; ++f) {
            da += vS[tid * E + f];
            dg += qS[tid * E + f];
        }
        qrow[tid] = dg;
    }
    __syncthreads();
    if (tid == 0) {
        float t = 0.f;
#pragma unroll
        for (int r = 0; r < 32; ++r) t += qrow[r];
        store_llc(&qpart[bx], t);
    }
    batch_barrier(&mybars[4 * B * BAR_PAD]);

    if (tid < 32) {
        float t = load_llc(&qpart[(b << 5) + tid]);
#pragma unroll
        for (int mask = 1; mask < 32; mask <<= 1)
            t += __shfl_xor(t, mask, 32);
        if (tid == 0) qsumS = t;
    }
    __syncthreads();
    if (tid < 32) qv[(b << 10) + i0 + tid] = da + qsumS;
}

extern "C" void kernel_launch(void* const* d_in, const int* in_sizes, int n_in,
                              void* d_out, int out_size, void* d_ws, size_t ws_size,
                              hipStream_t stream) {
    const float* features  = (const float*)d_in[0];
    const float* W         = (const float*)d_in[1];
    const float* adjacency = (const float*)d_in[2];
    const float* w_sel     = (const float*)d_in[3];
    const float* w_pri     = (const float*)d_in[4];
    const float* w_nbw     = (const float*)d_in[5];
    const float* w_ew      = (const float*)d_in[6];
    const float* w_reduc   = (const float*)d_in[7];
    const float* w_all     = (const float*)d_in[8];
    const float* w_act     = (const float*)d_in[9];

    float* out     = (float*)d_out;
    float* qv      = out;              // B*N
    float* emb_out = out + B * N;      // B*N*E

    float* ws      = (float*)d_ws;
    float* eA      = ws;                               // B*EMB_FLOATS
    float* eB      = eA + (size_t)B * EMB_FLOATS;
    float* qpart   = eB + (size_t)B * EMB_FLOATS;      // 256 floats
    unsigned* bars = (unsigned*)(qpart + NBLK);        // 5 stages x 8 batches x 128B

    // Pick k7 only if the allocator actually gave it a spill-free >=96-VGPR
    // allocation (host-side query, stream-independent, capture-safe; cached).
    static int use7 = -1;
    if (use7 < 0) {
        hipFuncAttributes fa{};
        use7 = 0;
        if (hipFuncGetAttributes(&fa, (const void*)k_fused7) == hipSuccess &&
            fa.localSizeBytes == 0 && fa.numRegs >= 96)
            use7 = 1;
    }

    hipMemsetAsync(bars, 0, 5 * B * BAR_PAD * sizeof(unsigned), stream);
    if (use7)
        k_fused7<<<NBLK, 1024, 0, stream>>>(W, features, w_sel, w_nbw, w_ew,
                                            adjacency, w_pri, w_reduc, w_all,
                                            w_act, eA, eB, emb_out, qv, qpart,
                                            bars);
    else
        k_fused6<<<NBLK, 1024, 0, stream>>>(W, features, w_sel, w_nbw, w_ew,
                                            adjacency, w_pri, w_reduc, w_all,
                                            w_act, eA, eB, emb_out, qv, qpart,
                                            bars);
}